// Round 7
// baseline (784.096 us; speedup 1.0000x reference)
//
#include <hip/hip_runtime.h>

typedef __attribute__((ext_vector_type(8))) short short8;
typedef __attribute__((ext_vector_type(4))) float floatx4;
typedef unsigned short ushort_t;
typedef unsigned int uint32;

// ---------- helpers ----------

__device__ __forceinline__ uint32 f2bf_bits(float f) {
  uint32 u = __builtin_bit_cast(uint32, f);
  u += 0x7fffu + ((u >> 16) & 1u);   // round-to-nearest-even
  return u >> 16;
}

__device__ __forceinline__ float tanh_fast(float x) {
  float e = __expf(2.0f * x);
  return 1.0f - 2.0f * __builtin_amdgcn_rcpf(e + 1.0f);
}

#define MFMA16(a, b, c) __builtin_amdgcn_mfma_f32_16x16x32_bf16((a), (b), (c), 0, 0, 0)

// lgkm-only barrier: __syncthreads() drains vmcnt(0) (kills in-flight HBM/L2
// prefetch every group). All cross-wave dataflow here is via LDS, so
// lgkmcnt(0) + s_barrier is sufficient for correctness.
#define BAR_LGKM() asm volatile("s_waitcnt lgkmcnt(0)\n\ts_barrier" ::: "memory")

// conv: 8x float4 fp32 -> bf16 (round-half-up) -> LDS via byte-perm pack
__device__ __forceinline__ void conv_store(const float4 (&rx)[8], uint32* sxw) {
#pragma unroll
  for (int p = 0; p < 8; ++p) {
    uint32 bx = __builtin_bit_cast(uint32, rx[p].x) + 0x8000u;
    uint32 by = __builtin_bit_cast(uint32, rx[p].y) + 0x8000u;
    uint32 bz = __builtin_bit_cast(uint32, rx[p].z) + 0x8000u;
    uint32 bw = __builtin_bit_cast(uint32, rx[p].w) + 0x8000u;
    uint32 lo = __builtin_amdgcn_perm(by, bx, 0x07060302u);
    uint32 hi = __builtin_amdgcn_perm(bw, bz, 0x07060302u);
    *(uint2*)(sxw + p * 16) = make_uint2(lo, hi);
  }
}

// ---------- prep: fold weights, cast bf16, emit FRAGMENT-MAJOR layouts ----------
// Wtm2 panels: p = (g*8 + nb)*8 + kk ; Wtr2 panels: q = (g*16 + nb)*4 + kk2
// (512 ushorts = 1 KB per panel; offset kh*128 + l15*8 + e)
// ws layout: Wtm2 1MB @0 | Wtr2 1MB @1MB | bias_eff @2MB | part @4MB

__global__ __launch_bounds__(256) void prep(const float* __restrict__ w_inp,
                                            const float* __restrict__ pbias,
                                            const float* __restrict__ W_mid,
                                            const float* __restrict__ b_mid,
                                            const float* __restrict__ W_root,
                                            ushort_t* __restrict__ Wtm2,
                                            ushort_t* __restrict__ Wtr2,
                                            float* __restrict__ bias_eff) {
  __shared__ float tl[32][33];
  __shared__ float red[256];
  const int b = blockIdx.x, t = threadIdx.x;
  const int tx = t & 31, ty = t >> 5;              // load-phase coords

  if (b < 512) {
    const int g = b >> 5, tile = b & 31;
    const int i0 = (tile >> 2) * 32, o0 = (tile & 3) * 32;
#pragma unroll
    for (int r = 0; r < 4; ++r) {
      const int il = ty * 4 + r;
      tl[il][tx] = W_mid[(g << 15) + (i0 + il) * 128 + o0 + tx] * w_inp[g * 256 + i0 + il];
    }
    __syncthreads();
    const int nl = t >> 3, s = t & 7;              // store-phase coords
    const int o = o0 + nl, nb = o >> 4, l15 = o & 15;
    const int kk = i0 >> 5;
    const int iloc = s * 4, kh = iloc >> 3, e0 = iloc & 7;
    const uint32 lo = (uint32)f2bf_bits(tl[iloc + 0][nl]) |
                      ((uint32)f2bf_bits(tl[iloc + 1][nl]) << 16);
    const uint32 hi = (uint32)f2bf_bits(tl[iloc + 2][nl]) |
                      ((uint32)f2bf_bits(tl[iloc + 3][nl]) << 16);
    uint2* dst = (uint2*)(Wtm2 + (size_t)(((g * 8 + nb) * 8 + kk) * 512 + kh * 128 + l15 * 8 + e0));
    *dst = make_uint2(lo, hi);
  } else if (b < 1024) {
    const int bb = b - 512;
    const int k0 = (bb >> 3) * 32, o0 = (bb & 7) * 32;
#pragma unroll
    for (int r = 0; r < 4; ++r) {
      const int kl = ty * 4 + r;
      tl[kl][tx] = W_root[(k0 + kl) * 256 + o0 + tx];
    }
    __syncthreads();
    const int nl = t >> 3, s = t & 7;
    const int o = o0 + nl, nb = o >> 4, l15 = o & 15;
    const int g = k0 >> 7, kk2 = (k0 >> 5) & 3;
    const int iloc = s * 4, kh = iloc >> 3, e0 = iloc & 7;
    const uint32 lo = (uint32)f2bf_bits(tl[iloc + 0][nl]) |
                      ((uint32)f2bf_bits(tl[iloc + 1][nl]) << 16);
    const uint32 hi = (uint32)f2bf_bits(tl[iloc + 2][nl]) |
                      ((uint32)f2bf_bits(tl[iloc + 3][nl]) << 16);
    uint2* dst = (uint2*)(Wtr2 + (size_t)(((g * 16 + nb) * 4 + kk2) * 512 + kh * 128 + l15 * 8 + e0));
    *dst = make_uint2(lo, hi);
  } else {
    const int g = b - 1024;
    const int o = t & 127, ih = t >> 7;
    const float* wp = W_mid + (g << 15) + ih * 128 * 128 + o;
    const float pb0 = pbias[g * 4 + ih * 2];
    const float pb1 = pbias[g * 4 + ih * 2 + 1];
    float s = 0.f;
#pragma unroll 8
    for (int ii = 0; ii < 128; ++ii) s += (ii < 64 ? pb0 : pb1) * wp[ii * 128];
    red[t] = s;
    __syncthreads();
    if (ih == 0) bias_eff[g * 128 + o] = b_mid[g * 128 + o] + red[o] + red[128 + o];
  }
}

// ---------- fused mid+root (REAL path, identical to v6) ----------

template <bool SPLIT>
__global__ __launch_bounds__(512, 2) void fused(const float* __restrict__ x,
                                                const ushort_t* __restrict__ Wtm2,
                                                const ushort_t* __restrict__ Wtr2,
                                                const float* __restrict__ bias_eff,
                                                const float* __restrict__ b_root,
                                                float* __restrict__ dst) {
  constexpr int GROUPS = SPLIT ? 8 : 16;

  __shared__ __align__(16) ushort_t sX[64 * 264];   // 33.8 KB
  __shared__ __align__(16) ushort_t sMid[64 * 136]; // 17.4 KB

  const int t = threadIdx.x;
  const int lane = t & 63;
  const int w = __builtin_amdgcn_readfirstlane(t >> 6);   // wave 0..7
  const int tile = SPLIT ? (int)(blockIdx.x >> 1) : (int)blockIdx.x;
  const int h = SPLIT ? (int)(blockIdx.x & 1) : 0;
  const int G0 = h * 8;
  const int m0 = tile * 64;
  const int l15 = lane & 15;
  const int kh = lane >> 4;

  const int xr = t >> 3, xq = t & 7;
  const float* xbase = x + (size_t)(m0 + xr) * 4096 + (size_t)G0 * 256 + xq * 4;
  uint32* sxw = (uint32*)(sX + xr * 264 + xq * 4);

  const ushort_t* sxa = sX + l15 * 264 + kh * 8;
  const ushort_t* sma = sMid + l15 * 136 + kh * 8;

  const ushort_t* wtm_u = Wtm2 + (((size_t)G0) << 15) + w * 4096;
  const ushort_t* wtr_u = Wtr2 + (((size_t)G0) << 15) + w * 4096;
  const int wlo = lane * 8;

  float4 rx[8];
  floatx4 racc[4][2] = {};

#pragma unroll
  for (int p = 0; p < 8; ++p) rx[p] = *(const float4*)(xbase + p * 32);

#pragma unroll 1
  for (int g = 0; g < GROUPS; ++g) {
    const int gw = g << 15;

    short8 mb[4];
#pragma unroll
    for (int kk = 0; kk < 4; ++kk) mb[kk] = *(const short8*)(wtm_u + gw + kk * 512 + wlo);
    const float bias = bias_eff[(G0 + g) * 128 + w * 16 + l15];

    conv_store(rx, sxw);

    if (g < GROUPS - 1) {
      const float* xn = xbase + (g + 1) * 256;
#pragma unroll
      for (int p = 0; p < 8; ++p) rx[p] = *(const float4*)(xn + p * 32);
    }
    __builtin_amdgcn_sched_barrier(0);

    BAR_LGKM();  // (B) sX ready

    floatx4 macc[4] = {};
#pragma unroll
    for (int kk = 0; kk < 8; ++kk) {
      short8 a0 = *(const short8*)(sxa + 0 * 16 * 264 + kk * 32);
      short8 a1 = *(const short8*)(sxa + 1 * 16 * 264 + kk * 32);
      short8 a2 = *(const short8*)(sxa + 2 * 16 * 264 + kk * 32);
      short8 a3 = *(const short8*)(sxa + 3 * 16 * 264 + kk * 32);
      short8 b = mb[kk & 3];
      if (kk < 4) mb[kk & 3] = *(const short8*)(wtm_u + gw + (kk + 4) * 512 + wlo);
      macc[0] = MFMA16(a0, b, macc[0]);
      macc[1] = MFMA16(a1, b, macc[1]);
      macc[2] = MFMA16(a2, b, macc[2]);
      macc[3] = MFMA16(a3, b, macc[3]);
    }

    __builtin_amdgcn_sched_barrier(0);

    short8 rb[2][2];
#pragma unroll
    for (int ni = 0; ni < 2; ++ni) rb[0][ni] = *(const short8*)(wtr_u + gw + (ni * 4 + 0) * 512 + wlo);
#pragma unroll
    for (int ni = 0; ni < 2; ++ni) rb[1][ni] = *(const short8*)(wtr_u + gw + (ni * 4 + 1) * 512 + wlo);

    {
      const int col = w * 16 + l15;
#pragma unroll
      for (int af = 0; af < 4; ++af)
#pragma unroll
        for (int r = 0; r < 4; ++r) {
          const int row = af * 16 + kh * 4 + r;
          sMid[row * 136 + col] = (ushort_t)f2bf_bits(tanh_fast(macc[af][r] + bias));
        }
    }

    BAR_LGKM();  // (C) sMid ready

#pragma unroll
    for (int kk2 = 0; kk2 < 4; ++kk2) {
      short8 a0 = *(const short8*)(sma + 0 * 16 * 136 + kk2 * 32);
      short8 a1 = *(const short8*)(sma + 1 * 16 * 136 + kk2 * 32);
      short8 a2 = *(const short8*)(sma + 2 * 16 * 136 + kk2 * 32);
      short8 a3 = *(const short8*)(sma + 3 * 16 * 136 + kk2 * 32);
      short8 b0 = rb[kk2 & 1][0], b1 = rb[kk2 & 1][1];
      if (kk2 < 2) {
#pragma unroll
        for (int ni = 0; ni < 2; ++ni)
          rb[kk2 & 1][ni] = *(const short8*)(wtr_u + gw + (ni * 4 + kk2 + 2) * 512 + wlo);
      }
      racc[0][0] = MFMA16(a0, b0, racc[0][0]);
      racc[0][1] = MFMA16(a0, b1, racc[0][1]);
      racc[1][0] = MFMA16(a1, b0, racc[1][0]);
      racc[1][1] = MFMA16(a1, b1, racc[1][1]);
      racc[2][0] = MFMA16(a2, b0, racc[2][0]);
      racc[2][1] = MFMA16(a2, b1, racc[2][1]);
      racc[3][0] = MFMA16(a3, b0, racc[3][0]);
      racc[3][1] = MFMA16(a3, b1, racc[3][1]);
    }
  }

  float* o = SPLIT ? dst + (size_t)h * (16384 * 256) : dst;
#pragma unroll
  for (int ni = 0; ni < 2; ++ni) {
    const int col = w * 32 + ni * 16 + l15;
    const float br = SPLIT ? 0.0f : b_root[col];
#pragma unroll
    for (int af = 0; af < 4; ++af)
#pragma unroll
      for (int r = 0; r < 4; ++r) {
        const int row = m0 + af * 16 + kh * 4 + r;
        o[(size_t)row * 256 + col] = racc[af][ni][r] + br;
      }
  }
}

// ---------- DIAGNOSTIC probes (run after real path, write scratch) ----------
// V=0: full loop (control).  V=1: no weight loads (constant frags).
// V=2: no x load / no conv (sX written once in prologue).
// REPEAT amplifies the loop so each probe rises above the ~160 µs fill
// dispatches in rocprof's top-5, yielding per-phase dur + counters.

template <int V, int REPEAT>
__global__ __launch_bounds__(512, 2) void probe(const float* __restrict__ x,
                                                const ushort_t* __restrict__ Wtm2,
                                                const ushort_t* __restrict__ Wtr2,
                                                const float* __restrict__ bias_eff,
                                                float* __restrict__ dst) {
  constexpr int GROUPS = 8;

  __shared__ __align__(16) ushort_t sX[64 * 264];
  __shared__ __align__(16) ushort_t sMid[64 * 136];

  const int t = threadIdx.x;
  const int lane = t & 63;
  const int w = __builtin_amdgcn_readfirstlane(t >> 6);
  const int tile = (int)(blockIdx.x >> 1);
  const int h = (int)(blockIdx.x & 1);
  const int G0 = h * 8;
  const int m0 = tile * 64;
  const int l15 = lane & 15;
  const int kh = lane >> 4;

  const int xr = t >> 3, xq = t & 7;
  const float* xbase = x + (size_t)(m0 + xr) * 4096 + (size_t)G0 * 256 + xq * 4;
  uint32* sxw = (uint32*)(sX + xr * 264 + xq * 4);

  const ushort_t* sxa = sX + l15 * 264 + kh * 8;
  const ushort_t* sma = sMid + l15 * 136 + kh * 8;

  const ushort_t* wtm_u = Wtm2 + (((size_t)G0) << 15) + w * 4096;
  const ushort_t* wtr_u = Wtr2 + (((size_t)G0) << 15) + w * 4096;
  const int wlo = lane * 8;

  float4 rx[8];
  floatx4 racc[4][2] = {};

  short8 wdum0, wdum1;
  if (V == 1) {
    wdum0 = *(const short8*)(wtm_u + wlo);
    wdum1 = *(const short8*)(wtr_u + wlo);
  }

#pragma unroll
  for (int p = 0; p < 8; ++p) rx[p] = *(const float4*)(xbase + p * 32);
  if (V == 2) conv_store(rx, sxw);   // sX filled once; loop reuses it

#pragma unroll 1
  for (int rep = 0; rep < REPEAT; ++rep) {
#pragma unroll 1
    for (int g = 0; g < GROUPS; ++g) {
      const int gw = g << 15;

      short8 mb[4];
      if (V == 1) {
        mb[0] = wdum0; mb[1] = wdum0; mb[2] = wdum0; mb[3] = wdum0;
      } else {
#pragma unroll
        for (int kk = 0; kk < 4; ++kk) mb[kk] = *(const short8*)(wtm_u + gw + kk * 512 + wlo);
      }
      const float bias = bias_eff[(G0 + g) * 128 + w * 16 + l15];

      if (V != 2) {
        conv_store(rx, sxw);
        const float* xn = xbase + ((g + 1) & 7) * 256;   // wraps; junk data ok
#pragma unroll
        for (int p = 0; p < 8; ++p) rx[p] = *(const float4*)(xn + p * 32);
        __builtin_amdgcn_sched_barrier(0);
      }

      BAR_LGKM();  // (B)

      floatx4 macc[4] = {};
#pragma unroll
      for (int kk = 0; kk < 8; ++kk) {
        short8 a0 = *(const short8*)(sxa + 0 * 16 * 264 + kk * 32);
        short8 a1 = *(const short8*)(sxa + 1 * 16 * 264 + kk * 32);
        short8 a2 = *(const short8*)(sxa + 2 * 16 * 264 + kk * 32);
        short8 a3 = *(const short8*)(sxa + 3 * 16 * 264 + kk * 32);
        short8 b = mb[kk & 3];
        if (V != 1 && kk < 4) mb[kk & 3] = *(const short8*)(wtm_u + gw + (kk + 4) * 512 + wlo);
        macc[0] = MFMA16(a0, b, macc[0]);
        macc[1] = MFMA16(a1, b, macc[1]);
        macc[2] = MFMA16(a2, b, macc[2]);
        macc[3] = MFMA16(a3, b, macc[3]);
      }

      __builtin_amdgcn_sched_barrier(0);

      short8 rb[2][2];
      if (V == 1) {
        rb[0][0] = wdum1; rb[0][1] = wdum1; rb[1][0] = wdum1; rb[1][1] = wdum1;
      } else {
#pragma unroll
        for (int ni = 0; ni < 2; ++ni) rb[0][ni] = *(const short8*)(wtr_u + gw + (ni * 4 + 0) * 512 + wlo);
#pragma unroll
        for (int ni = 0; ni < 2; ++ni) rb[1][ni] = *(const short8*)(wtr_u + gw + (ni * 4 + 1) * 512 + wlo);
      }

      {
        const int col = w * 16 + l15;
#pragma unroll
        for (int af = 0; af < 4; ++af)
#pragma unroll
          for (int r = 0; r < 4; ++r) {
            const int row = af * 16 + kh * 4 + r;
            sMid[row * 136 + col] = (ushort_t)f2bf_bits(tanh_fast(macc[af][r] + bias));
          }
      }

      BAR_LGKM();  // (C)

#pragma unroll
      for (int kk2 = 0; kk2 < 4; ++kk2) {
        short8 a0 = *(const short8*)(sma + 0 * 16 * 136 + kk2 * 32);
        short8 a1 = *(const short8*)(sma + 1 * 16 * 136 + kk2 * 32);
        short8 a2 = *(const short8*)(sma + 2 * 16 * 136 + kk2 * 32);
        short8 a3 = *(const short8*)(sma + 3 * 16 * 136 + kk2 * 32);
        short8 b0 = rb[kk2 & 1][0], b1 = rb[kk2 & 1][1];
        if (V != 1 && kk2 < 2) {
#pragma unroll
          for (int ni = 0; ni < 2; ++ni)
            rb[kk2 & 1][ni] = *(const short8*)(wtr_u + gw + (ni * 4 + kk2 + 2) * 512 + wlo);
        }
        racc[0][0] = MFMA16(a0, b0, racc[0][0]);
        racc[0][1] = MFMA16(a0, b1, racc[0][1]);
        racc[1][0] = MFMA16(a1, b0, racc[1][0]);
        racc[1][1] = MFMA16(a1, b1, racc[1][1]);
        racc[2][0] = MFMA16(a2, b0, racc[2][0]);
        racc[2][1] = MFMA16(a2, b1, racc[2][1]);
        racc[3][0] = MFMA16(a3, b0, racc[3][0]);
        racc[3][1] = MFMA16(a3, b1, racc[3][1]);
      }
    }
  }

  // keep everything live; scratch write (same footprint as fused<true>)
  float* o = dst + (size_t)h * (16384 * 256);
#pragma unroll
  for (int ni = 0; ni < 2; ++ni) {
    const int col = w * 32 + ni * 16 + l15;
#pragma unroll
    for (int af = 0; af < 4; ++af)
#pragma unroll
      for (int r = 0; r < 4; ++r) {
        const int row = m0 + af * 16 + kh * 4 + r;
        o[(size_t)row * 256 + col] = racc[af][ni][r];
      }
  }
}

// ---------- split-K reduce: out = p0 + p1 + b_root ----------

__global__ __launch_bounds__(256) void reducek(const float* __restrict__ part,
                                               const float* __restrict__ b_root,
                                               float* __restrict__ out) {
  const int i = blockIdx.x * 256 + threadIdx.x;
  float4 a = ((const float4*)part)[i];
  float4 c = ((const float4*)(part + (size_t)16384 * 256))[i];
  float4 br = ((const float4*)b_root)[i & 63];
  float4 r;
  r.x = a.x + c.x + br.x;
  r.y = a.y + c.y + br.y;
  r.z = a.z + c.z + br.z;
  r.w = a.w + c.w + br.w;
  ((float4*)out)[i] = r;
}

// ---------- launch ----------

extern "C" void kernel_launch(void* const* d_in, const int* in_sizes, int n_in,
                              void* d_out, int out_size, void* d_ws, size_t ws_size,
                              hipStream_t stream) {
  const float* x      = (const float*)d_in[0];
  const float* w_inp  = (const float*)d_in[1];
  const float* pbias  = (const float*)d_in[2];
  const float* W_mid  = (const float*)d_in[3];
  const float* b_mid  = (const float*)d_in[4];
  const float* W_root = (const float*)d_in[5];
  const float* b_root = (const float*)d_in[6];
  float* out = (float*)d_out;

  char* ws = (char*)d_ws;
  ushort_t* Wtm2     = (ushort_t*)(ws);
  ushort_t* Wtr2     = (ushort_t*)(ws + (1 << 20));
  float*    bias_eff = (float*)   (ws + (2 << 20));
  float*    part     = (float*)   (ws + (4 << 20));

  const size_t need = (size_t)(4 << 20) + 2ull * 16384 * 256 * 4;
  const bool split = ws_size >= need;

  prep<<<dim3(1040), dim3(256), 0, stream>>>(w_inp, pbias, W_mid, b_mid, W_root, Wtm2, Wtr2, bias_eff);
  if (split) {
    fused<true><<<dim3(512), dim3(512), 0, stream>>>(x, Wtm2, Wtr2, bias_eff, b_root, part);
    reducek<<<dim3(4096), dim3(256), 0, stream>>>(part, b_root, out);
    // ---- diagnostic probes (scratch writes to part; out already final) ----
    probe<0, 2><<<dim3(512), dim3(512), 0, stream>>>(x, Wtm2, Wtr2, bias_eff, part);
    probe<1, 3><<<dim3(512), dim3(512), 0, stream>>>(x, Wtm2, Wtr2, bias_eff, part);
    probe<2, 3><<<dim3(512), dim3(512), 0, stream>>>(x, Wtm2, Wtr2, bias_eff, part);
  } else {
    fused<false><<<dim3(256), dim3(512), 0, stream>>>(x, Wtm2, Wtr2, bias_eff, b_root, out);
  }
}